// Round 1
// baseline (167.268 us; speedup 1.0000x reference)
//
#include <hip/hip_runtime.h>
#include <hip/hip_bf16.h>

#define BB 8
#define NN 1024
#define FIN 512
#define HH 8
#define FOUT 64
#define HF 512
#define SLOPE 0.2f

static __device__ __forceinline__ float lrelu(float v) { return v > 0.0f ? v : SLOPE * v; }

static __device__ __forceinline__ unsigned short f2bf(float f) {
  __hip_bfloat16 h = __float2bfloat16(f);
  return *reinterpret_cast<unsigned short*>(&h);
}
static __device__ __forceinline__ float bf2f(unsigned short u) {
  __hip_bfloat16 h;
  *reinterpret_cast<unsigned short*>(&h) = u;
  return __bfloat162float(h);
}

// ---------------------------------------------------------------------------
// K0: detect adjacency storage format using the guaranteed self-loop diagonal.
// mode 1 = int32, mode 2 = float32, mode 0 = 1-byte bool
// ---------------------------------------------------------------------------
__global__ void k_detect(const void* __restrict__ adj, int* __restrict__ flag) {
  if (threadIdx.x == 0) {
    const int* ai = (const int*)adj;
    const float* af = (const float*)adj;
    const unsigned char* ab = (const unsigned char*)adj;
    bool oki = true, okf = true;
    for (int i = 0; i < 64; ++i) {
      int d = i * (NN + 1);
      oki = oki && (ai[d] == 1);
      okf = okf && (af[d] == 1.0f);
    }
    (void)ab;
    *flag = oki ? 1 : (okf ? 2 : 0);
  }
}

static __device__ __forceinline__ bool adj_at(const void* adj, int mode, size_t idx) {
  if (mode == 1) return ((const int*)adj)[idx] != 0;
  if (mode == 2) return ((const float*)adj)[idx] != 0.0f;
  return ((const unsigned char*)adj)[idx] != 0;
}

// ---------------------------------------------------------------------------
// K1: Wh = x @ W  (fp32 VALU tiled GEMM, 64x64 tile, 256 threads, 4x4/thread)
// Epilogue: Wh tile -> bf16 store; e_src/e_dst fp32 via 16-lane shfl reduce.
// blockIdx.x = row tile (0..127), blockIdx.y = head (0..7, col tile of 64)
// ---------------------------------------------------------------------------
__global__ __launch_bounds__(256) void k_gemm(
    const float* __restrict__ x, const float* __restrict__ W,
    const float* __restrict__ a,
    unsigned short* __restrict__ Wh, float* __restrict__ e_src,
    float* __restrict__ e_dst) {
  __shared__ __align__(16) float xT[32][68];  // transposed x tile [k][r]
  __shared__ __align__(16) float Wt[32][68];  // W tile [k][c]

  const int bm = blockIdx.x;
  const int bn = blockIdx.y;  // head
  const int t = threadIdx.x;
  const int tx = t & 15, ty = t >> 4;
  const int row0 = bm * 64, col0 = bn * 64;

  float acc[4][4] = {};

  for (int k0 = 0; k0 < FIN; k0 += 32) {
    // stage x tile transposed: 64 rows x 32 k
    int idx = t;
#pragma unroll
    for (int it = 0; it < 2; ++it) {
      int r = idx >> 3, kq = (idx & 7) * 4;
      float4 v = *(const float4*)(x + (size_t)(row0 + r) * FIN + k0 + kq);
      xT[kq + 0][r] = v.x;
      xT[kq + 1][r] = v.y;
      xT[kq + 2][r] = v.z;
      xT[kq + 3][r] = v.w;
      idx += 256;
    }
    // stage W tile: 32 k x 64 cols
    int idxw = t;
#pragma unroll
    for (int it = 0; it < 2; ++it) {
      int k = idxw >> 4, cq = (idxw & 15) * 4;
      float4 v = *(const float4*)(W + (size_t)(k0 + k) * HF + col0 + cq);
      *(float4*)&Wt[k][cq] = v;
      idxw += 256;
    }
    __syncthreads();
#pragma unroll
    for (int k = 0; k < 32; ++k) {
      float av[4], bv[4];
      *(float4*)av = *(const float4*)&xT[k][ty * 4];
      *(float4*)bv = *(const float4*)&Wt[k][tx * 4];
#pragma unroll
      for (int i = 0; i < 4; ++i)
#pragma unroll
        for (int j = 0; j < 4; ++j) acc[i][j] += av[i] * bv[j];
    }
    __syncthreads();
  }

  // store bf16 Wh
#pragma unroll
  for (int i = 0; i < 4; ++i) {
    int r = row0 + ty * 4 + i;
    ushort4 o;
    o.x = f2bf(acc[i][0]);
    o.y = f2bf(acc[i][1]);
    o.z = f2bf(acc[i][2]);
    o.w = f2bf(acc[i][3]);
    *reinterpret_cast<ushort4*>(Wh + (size_t)r * HF + col0 + tx * 4) = o;
  }

  // epilogue: e_src/e_dst for this head, fp32 from accumulators
  float4 av_s = *(const float4*)(a + bn * 2 * FOUT + tx * 4);
  float4 av_d = *(const float4*)(a + bn * 2 * FOUT + FOUT + tx * 4);
#pragma unroll
  for (int i = 0; i < 4; ++i) {
    float ps = acc[i][0] * av_s.x + acc[i][1] * av_s.y + acc[i][2] * av_s.z +
               acc[i][3] * av_s.w;
    float pd = acc[i][0] * av_d.x + acc[i][1] * av_d.y + acc[i][2] * av_d.z +
               acc[i][3] * av_d.w;
#pragma unroll
    for (int s = 1; s < 16; s <<= 1) {
      ps += __shfl_xor(ps, s, 16);
      pd += __shfl_xor(pd, s, 16);
    }
    if (tx == 0) {
      size_t r = (size_t)(row0 + ty * 4 + i);
      e_src[r * HH + bn] = ps;
      e_dst[r * HH + bn] = pd;
    }
  }
}

// ---------------------------------------------------------------------------
// K2: fused sparse attention + skip + LayerNorm. One block per (b,i).
// ---------------------------------------------------------------------------
__global__ __launch_bounds__(256) void k_attn(
    const float* __restrict__ x, const void* __restrict__ adj,
    const int* __restrict__ flag, const unsigned short* __restrict__ Wh,
    const float* __restrict__ e_src, const float* __restrict__ e_dst,
    const float* __restrict__ gamma, const float* __restrict__ beta,
    float* __restrict__ out) {
  __shared__ unsigned short nbrs[NN];
  __shared__ float edbuf[128][9];
  __shared__ float esb[HH];
  __shared__ float hacc[HF];
  __shared__ int wcount[4];
  __shared__ float rs[4], rss[4];

  const int bi = blockIdx.x;
  const int b = bi >> 10, i = bi & (NN - 1);
  const int t = threadIdx.x;
  const int wave = t >> 6, lane = t & 63;
  const int mode = *flag;
  const size_t arow = ((size_t)b * NN + i) * NN;

  // ---- phase 1: deterministic neighbor compaction (ballot + prefix) ----
  unsigned long long masks[4];
  int mycnt = 0;
#pragma unroll
  for (int s = 0; s < 4; ++s) {
    int j = wave * 256 + s * 64 + lane;
    bool v = adj_at(adj, mode, arow + j);
    unsigned long long m = __ballot(v);
    masks[s] = m;
    mycnt += __popcll(m);
  }
  if (lane == 0) wcount[wave] = mycnt;
  __syncthreads();
  int off = 0;
  for (int w2 = 0; w2 < wave; ++w2) off += wcount[w2];
  const int total = wcount[0] + wcount[1] + wcount[2] + wcount[3];
#pragma unroll
  for (int s = 0; s < 4; ++s) {
    unsigned long long m = masks[s];
    if ((m >> lane) & 1ull) {
      int pos = off + __popcll(m & ((1ull << lane) - 1ull));
      nbrs[pos] = (unsigned short)(wave * 256 + s * 64 + lane);
    }
    off += __popcll(m);
  }
  __syncthreads();

  // ---- phase 1b: stage e_src row + e_dst of first <=128 neighbors ----
  if (t < HH) esb[t] = e_src[((size_t)b * NN + i) * HH + t];
  const int ncap = total < 128 ? total : 128;
  for (int kk = t; kk < ncap * HH; kk += 256) {
    int k = kk >> 3, h = kk & 7;
    edbuf[k][h] = e_dst[((size_t)b * NN + nbrs[k]) * HH + h];
  }
  __syncthreads();

  // ---- phase 2: per-wave, 2 heads each ----
  for (int hh = 0; hh < 2; ++hh) {
    const int h = wave * 2 + hh;
    const float es = esb[h];
    // row max of e_dst over neighbors (lrelu is monotone -> exact row max)
    float mx = -1e30f;
    for (int k = lane; k < total; k += 64) {
      float ed = (k < 128) ? edbuf[k][h]
                           : e_dst[((size_t)b * NN + nbrs[k]) * HH + h];
      mx = fmaxf(mx, ed);
    }
#pragma unroll
    for (int s = 32; s > 0; s >>= 1) mx = fmaxf(mx, __shfl_xor(mx, s));
    const float rowmax = lrelu(es + mx);
    // Z
    float z = 0.0f;
    for (int k = lane; k < total; k += 64) {
      float ed = (k < 128) ? edbuf[k][h]
                           : e_dst[((size_t)b * NN + nbrs[k]) * HH + h];
      z += __expf(lrelu(es + ed) - rowmax);
    }
#pragma unroll
    for (int s = 32; s > 0; s >>= 1) z += __shfl_xor(z, s);
    const float inv = 1.0f / z;
    // weighted accumulation: lane = feature
    float acc = 0.0f;
    for (int k = 0; k < total; ++k) {
      float ed = (k < 128) ? edbuf[k][h]
                           : e_dst[((size_t)b * NN + nbrs[k]) * HH + h];
      float w = __expf(lrelu(es + ed) - rowmax);
      int j = nbrs[k];
      acc += w * bf2f(Wh[(((size_t)b * NN + j) * HH + h) * FOUT + lane]);
    }
    hacc[h * FOUT + lane] = acc * inv;
  }
  __syncthreads();

  // ---- phase 3: skip + LayerNorm over 512 features ----
  const size_t xo = ((size_t)b * NN + i) * HF;
  float v0 = hacc[t] + x[xo + t];
  float v1 = hacc[t + 256] + x[xo + t + 256];
  float s = v0 + v1, ss = v0 * v0 + v1 * v1;
#pragma unroll
  for (int sft = 32; sft > 0; sft >>= 1) {
    s += __shfl_xor(s, sft);
    ss += __shfl_xor(ss, sft);
  }
  if (lane == 0) {
    rs[wave] = s;
    rss[wave] = ss;
  }
  __syncthreads();
  const float S = rs[0] + rs[1] + rs[2] + rs[3];
  const float SS = rss[0] + rss[1] + rss[2] + rss[3];
  const float mu = S * (1.0f / 512.0f);
  const float var = SS * (1.0f / 512.0f) - mu * mu;
  const float rstd = rsqrtf(var + 1e-5f);
  out[xo + t] = (v0 - mu) * rstd * gamma[t] + beta[t];
  out[xo + t + 256] = (v1 - mu) * rstd * gamma[t + 256] + beta[t + 256];
}

extern "C" void kernel_launch(void* const* d_in, const int* in_sizes, int n_in,
                              void* d_out, int out_size, void* d_ws,
                              size_t ws_size, hipStream_t stream) {
  const float* x = (const float*)d_in[0];
  const void* adj = d_in[1];
  const float* W = (const float*)d_in[2];
  const float* a = (const float*)d_in[3];
  const float* gamma = (const float*)d_in[4];
  const float* beta = (const float*)d_in[5];
  float* out = (float*)d_out;

  char* ws = (char*)d_ws;
  int* flag = (int*)ws;
  unsigned short* Wh = (unsigned short*)(ws + 256);
  float* e_src = (float*)(ws + 256 + (size_t)BB * NN * HF * 2);
  float* e_dst = e_src + (size_t)BB * NN * HH;

  k_detect<<<1, 64, 0, stream>>>(adj, flag);
  k_gemm<<<dim3(128, 8), 256, 0, stream>>>(x, W, a, Wh, e_src, e_dst);
  k_attn<<<BB * NN, 256, 0, stream>>>(x, adj, flag, Wh, e_src, e_dst, gamma,
                                      beta, out);
}

// Round 2
// 80.012 us; speedup vs baseline: 2.0905x; 2.0905x over previous
//
#include <hip/hip_runtime.h>
#include <hip/hip_bf16.h>

#define BB 8
#define NN 1024
#define FIN 512
#define HH 8
#define FOUT 64
#define HF 512
#define SLOPE 0.2f
#define NCAP 224

typedef __attribute__((ext_vector_type(8))) short bf16x8;
typedef __attribute__((ext_vector_type(4))) float f32x4;

static __device__ __forceinline__ float lrelu(float v) { return v > 0.0f ? v : SLOPE * v; }

static __device__ __forceinline__ unsigned short f2bf(float f) {
  __hip_bfloat16 h = __float2bfloat16(f);
  return *reinterpret_cast<unsigned short*>(&h);
}
static __device__ __forceinline__ float bflo(unsigned v) {
  unsigned u = v << 16;
  return *reinterpret_cast<float*>(&u);
}
static __device__ __forceinline__ float bfhi(unsigned v) {
  unsigned u = v & 0xffff0000u;
  return *reinterpret_cast<float*>(&u);
}

// ---------------------------------------------------------------------------
// K0: detect adjacency storage format via the guaranteed self-loop diagonal.
// mode 1 = int32, mode 2 = float32, mode 0 = 1-byte bool
// ---------------------------------------------------------------------------
__global__ void k_detect(const void* __restrict__ adj, int* __restrict__ flag) {
  if (threadIdx.x == 0) {
    const int* ai = (const int*)adj;
    const float* af = (const float*)adj;
    bool oki = true, okf = true;
    for (int i = 0; i < 64; ++i) {
      int d = i * (NN + 1);
      oki = oki && (ai[d] == 1);
      okf = okf && (af[d] == 1.0f);
    }
    *flag = oki ? 1 : (okf ? 2 : 0);
  }
}

// ---------------------------------------------------------------------------
// K1: transpose + cast W (FIN x HF, f32) -> Wt (HF x FIN, bf16)
// ---------------------------------------------------------------------------
__global__ __launch_bounds__(256) void k_prep(const float* __restrict__ W,
                                              unsigned short* __restrict__ Wt) {
  __shared__ float tile[64][65];
  const int t = threadIdx.x;
  const int r0 = blockIdx.y * 64, c0 = blockIdx.x * 64;
#pragma unroll
  for (int p = 0; p < 16; ++p) {
    int r = (t >> 6) + p * 4;
    tile[t & 63][r] = W[(size_t)(r0 + r) * HF + c0 + (t & 63)];
  }
  __syncthreads();
#pragma unroll
  for (int p = 0; p < 16; ++p) {
    int cc = (t >> 6) + p * 4;
    int rr = t & 63;
    Wt[(size_t)(c0 + cc) * FIN + r0 + rr] = f2bf(tile[cc][rr]);
  }
}

// ---------------------------------------------------------------------------
// K2: Wh = x @ W via bf16 MFMA. 64x64x64 tile, 256 threads (2x2 waves),
// each wave 32x32 (2x2 frags of 16x16x32). XOR-swizzled LDS, reg-staging.
// A = x (f32, cvt inline), B = Wt (bf16, [n][k]).
// ---------------------------------------------------------------------------
__global__ __launch_bounds__(256) void k_gemm(const float* __restrict__ x,
                                              const unsigned short* __restrict__ Wt,
                                              unsigned short* __restrict__ Wh) {
  __shared__ short As[64 * 64];  // [row][64 k] bf16, 16B-chunk swizzled
  __shared__ short Bs[64 * 64];  // [col][64 k]

  const int t = threadIdx.x;
  const int wave = t >> 6, lane = t & 63;
  const int wr = wave >> 1, wc = wave & 1;
  const int row0 = blockIdx.x * 64, col0 = blockIdx.y * 64;

  f32x4 acc[2][2] = {};

  const int sr = t >> 3;   // slot row 0..31 (second slot +32)
  const int skc = t & 7;   // slot 16B-chunk in row

  for (int k0 = 0; k0 < FIN; k0 += 64) {
    __syncthreads();
    // ---- stage A (f32 -> bf16) and B (bf16 copy), swizzled chunk = kc ^ (row&7)
#pragma unroll
    for (int ss = 0; ss < 2; ++ss) {
      const int row = sr + ss * 32;
      const int ksrc = k0 + ((skc ^ (row & 7)) << 3);
      const float4* g = (const float4*)(x + (size_t)(row0 + row) * FIN + ksrc);
      float4 v0 = g[0], v1 = g[1];
      bf16x8 pk;
      unsigned short* u = (unsigned short*)&pk;
      u[0] = f2bf(v0.x); u[1] = f2bf(v0.y); u[2] = f2bf(v0.z); u[3] = f2bf(v0.w);
      u[4] = f2bf(v1.x); u[5] = f2bf(v1.y); u[6] = f2bf(v1.z); u[7] = f2bf(v1.w);
      *(bf16x8*)(&As[row * 64 + skc * 8]) = pk;

      uint4 wv = *(const uint4*)(Wt + (size_t)(col0 + row) * FIN + ksrc);
      *(uint4*)(&Bs[row * 64 + skc * 8]) = wv;
    }
    __syncthreads();
    // ---- compute: 2 k-substeps of 32
#pragma unroll
    for (int s = 0; s < 2; ++s) {
      const int kc = s * 4 + (lane >> 4);
      bf16x8 af[2], bfr[2];
#pragma unroll
      for (int m = 0; m < 2; ++m) {
        const int row = wr * 32 + m * 16 + (lane & 15);
        af[m] = *(const bf16x8*)(&As[row * 64 + (kc ^ (row & 7)) * 8]);
      }
#pragma unroll
      for (int n = 0; n < 2; ++n) {
        const int col = wc * 32 + n * 16 + (lane & 15);
        bfr[n] = *(const bf16x8*)(&Bs[col * 64 + (kc ^ (col & 7)) * 8]);
      }
#pragma unroll
      for (int m = 0; m < 2; ++m)
#pragma unroll
        for (int n = 0; n < 2; ++n)
          acc[m][n] = __builtin_amdgcn_mfma_f32_16x16x32_bf16(af[m], bfr[n], acc[m][n], 0, 0, 0);
    }
  }

  // ---- epilogue: C/D layout col=lane&15, row=(lane>>4)*4+r
#pragma unroll
  for (int m = 0; m < 2; ++m)
#pragma unroll
    for (int n = 0; n < 2; ++n)
#pragma unroll
      for (int r = 0; r < 4; ++r) {
        const int row = row0 + wr * 32 + m * 16 + (lane >> 4) * 4 + r;
        const int col = col0 + wc * 32 + n * 16 + (lane & 15);
        Wh[(size_t)row * HF + col] = f2bf(acc[m][n][r]);
      }
}

// ---------------------------------------------------------------------------
// K3: e_src/e_dst from bf16 Wh. One wave per row; lane l: head l/8, 8 feats.
// ---------------------------------------------------------------------------
__global__ __launch_bounds__(256) void k_edge(const unsigned short* __restrict__ Wh,
                                              const float* __restrict__ a,
                                              float* __restrict__ e_src,
                                              float* __restrict__ e_dst) {
  const int row = blockIdx.x * 4 + (threadIdx.x >> 6);
  const int lane = threadIdx.x & 63;
  const int h = lane >> 3, fq = lane & 7;

  uint4 v = *(const uint4*)(Wh + (size_t)row * HF + h * 64 + fq * 8);
  const float4* ap = (const float4*)(a + h * 128 + fq * 8);
  float4 as0 = ap[0], as1 = ap[1];
  const float4* dp = (const float4*)(a + h * 128 + 64 + fq * 8);
  float4 ad0 = dp[0], ad1 = dp[1];

  float f0 = bflo(v.x), f1 = bfhi(v.x), f2 = bflo(v.y), f3 = bfhi(v.y);
  float f4 = bflo(v.z), f5 = bfhi(v.z), f6 = bflo(v.w), f7 = bfhi(v.w);

  float s = f0 * as0.x + f1 * as0.y + f2 * as0.z + f3 * as0.w +
            f4 * as1.x + f5 * as1.y + f6 * as1.z + f7 * as1.w;
  float d = f0 * ad0.x + f1 * ad0.y + f2 * ad0.z + f3 * ad0.w +
            f4 * ad1.x + f5 * ad1.y + f6 * ad1.z + f7 * ad1.w;
#pragma unroll
  for (int sh = 1; sh < 8; sh <<= 1) {
    s += __shfl_xor(s, sh);
    d += __shfl_xor(d, sh);
  }
  if (fq == 0) {
    e_src[(size_t)row * HH + h] = s;
    e_dst[(size_t)row * HH + h] = d;
  }
}

// ---------------------------------------------------------------------------
// K4: fused sparse attention + skip + LayerNorm. One block per (b,i).
// ---------------------------------------------------------------------------
__global__ __launch_bounds__(256) void k_attn(
    const float* __restrict__ x, const void* __restrict__ adj,
    const int* __restrict__ flag, const unsigned short* __restrict__ Wh,
    const float* __restrict__ e_src, const float* __restrict__ e_dst,
    const float* __restrict__ gamma, const float* __restrict__ beta,
    float* __restrict__ out) {
  __shared__ unsigned short nbrs[NN];
  __shared__ float edbuf[NCAP][9];
  __shared__ unsigned jbase[NCAP];
  __shared__ float esb[HH];
  __shared__ float hacc[HF];
  __shared__ int wcount[4];
  __shared__ float rs[4], rss[4];

  const int bi = blockIdx.x;
  const int b = bi >> 10, i = bi & (NN - 1);
  const int t = threadIdx.x;
  const int wave = t >> 6, lane = t & 63;
  const int mode = *flag;
  const size_t arow = ((size_t)b * NN + i) * NN;

  // ---- phase 1: neighbor compaction, 4 j's per lane (ascending order) ----
  const int j0 = wave * 256 + lane * 4;
  bool v0, v1, v2, v3;
  if (mode == 1) {
    int4 q = *((const int4*)((const int*)adj + arow + j0));
    v0 = q.x != 0; v1 = q.y != 0; v2 = q.z != 0; v3 = q.w != 0;
  } else if (mode == 2) {
    float4 q = *((const float4*)((const float*)adj + arow + j0));
    v0 = q.x != 0.f; v1 = q.y != 0.f; v2 = q.z != 0.f; v3 = q.w != 0.f;
  } else {
    unsigned q = *((const unsigned*)((const unsigned char*)adj + arow + j0));
    v0 = (q & 0xffu) != 0; v1 = (q & 0xff00u) != 0;
    v2 = (q & 0xff0000u) != 0; v3 = (q >> 24) != 0;
  }
  unsigned long long m0 = __ballot(v0), m1 = __ballot(v1);
  unsigned long long m2 = __ballot(v2), m3 = __ballot(v3);
  const int mycnt = __popcll(m0) + __popcll(m1) + __popcll(m2) + __popcll(m3);
  if (lane == 0) wcount[wave] = mycnt;
  __syncthreads();
  int woff = 0;
  for (int w2 = 0; w2 < wave; ++w2) woff += wcount[w2];
  const int total = wcount[0] + wcount[1] + wcount[2] + wcount[3];
  {
    const unsigned long long below = (1ull << lane) - 1ull;
    int base = woff + __popcll(m0 & below) + __popcll(m1 & below) +
               __popcll(m2 & below) + __popcll(m3 & below);
    int c = 0;
    if (v0) nbrs[base + c++] = (unsigned short)(j0 + 0);
    if (v1) nbrs[base + c++] = (unsigned short)(j0 + 1);
    if (v2) nbrs[base + c++] = (unsigned short)(j0 + 2);
    if (v3) nbrs[base + c++] = (unsigned short)(j0 + 3);
  }
  __syncthreads();

  // ---- phase 1b: stage e_src row, jbase, e_dst tile ----
  if (t < HH) esb[t] = e_src[((size_t)b * NN + i) * HH + t];
  const int ncap = total < NCAP ? total : NCAP;
  for (int k = t; k < ncap; k += 256)
    jbase[k] = ((unsigned)(b * NN + nbrs[k])) * HF;
  for (int kk = t; kk < ncap * HH; kk += 256) {
    int k = kk >> 3, h = kk & 7;
    edbuf[k][h] = e_dst[((size_t)b * NN + nbrs[k]) * HH + h];
  }
  __syncthreads();

  // ---- phase 2a: per wave, heads 2w,2w+1: rowmax, Z, w*inv into edbuf ----
  float esA[2], rmA[2], invA[2];
#pragma unroll
  for (int hh = 0; hh < 2; ++hh) {
    const int h = wave * 2 + hh;
    const float es = esb[h];
    float mx = -1e30f;
    for (int k = lane; k < total; k += 64) {
      float ed = (k < NCAP) ? edbuf[k][h]
                            : e_dst[((size_t)b * NN + nbrs[k]) * HH + h];
      mx = fmaxf(mx, ed);
    }
#pragma unroll
    for (int s = 32; s > 0; s >>= 1) mx = fmaxf(mx, __shfl_xor(mx, s));
    const float rowmax = lrelu(es + mx);
    float z = 0.0f;
    for (int k = lane; k < total; k += 64) {
      float ed = (k < NCAP) ? edbuf[k][h]
                            : e_dst[((size_t)b * NN + nbrs[k]) * HH + h];
      float w = __expf(lrelu(es + ed) - rowmax);
      if (k < NCAP) edbuf[k][h] = w;
      z += w;
    }
#pragma unroll
    for (int s = 32; s > 0; s >>= 1) z += __shfl_xor(z, s);
    const float inv = 1.0f / z;
    for (int k = lane; k < ncap; k += 64) edbuf[k][h] *= inv;
    esA[hh] = es; rmA[hh] = rowmax; invA[hh] = inv;
  }
  __syncthreads();

  // ---- phase 2b: both heads at once; lane = u32 (2 bf16 feats) ----
  {
    const int half = lane >> 5;
    const int h = wave * 2 + half;
    const unsigned hoff = (unsigned)(wave * 128 + lane * 2);
    float a00 = 0, a01 = 0, a10 = 0, a11 = 0;
    float a20 = 0, a21 = 0, a30 = 0, a31 = 0;
    int k = 0;
    for (; k + 4 <= ncap; k += 4) {
      unsigned q0 = *(const unsigned*)(Wh + jbase[k + 0] + hoff);
      unsigned q1 = *(const unsigned*)(Wh + jbase[k + 1] + hoff);
      unsigned q2 = *(const unsigned*)(Wh + jbase[k + 2] + hoff);
      unsigned q3 = *(const unsigned*)(Wh + jbase[k + 3] + hoff);
      float w0 = edbuf[k + 0][h], w1 = edbuf[k + 1][h];
      float w2 = edbuf[k + 2][h], w3 = edbuf[k + 3][h];
      a00 += w0 * bflo(q0); a01 += w0 * bfhi(q0);
      a10 += w1 * bflo(q1); a11 += w1 * bfhi(q1);
      a20 += w2 * bflo(q2); a21 += w2 * bfhi(q2);
      a30 += w3 * bflo(q3); a31 += w3 * bfhi(q3);
    }
    for (; k < ncap; ++k) {
      unsigned q = *(const unsigned*)(Wh + jbase[k] + hoff);
      float w = edbuf[k][h];
      a00 += w * bflo(q); a01 += w * bfhi(q);
    }
    float accL = a00 + a10 + a20 + a30;
    float accH = a01 + a11 + a21 + a31;
    // rare tail: neighbors beyond NCAP
    const float esX = half ? esA[1] : esA[0];
    const float rmX = half ? rmA[1] : rmA[0];
    const float ivX = half ? invA[1] : invA[0];
    for (; k < total; ++k) {
      int j = nbrs[k];
      float ed = e_dst[((size_t)b * NN + j) * HH + h];
      float w = __expf(lrelu(esX + ed) - rmX) * ivX;
      unsigned q = *(const unsigned*)(Wh + ((unsigned)(b * NN + j)) * HF + hoff);
      accL += w * bflo(q); accH += w * bfhi(q);
    }
    hacc[wave * 128 + lane * 2] = accL;
    hacc[wave * 128 + lane * 2 + 1] = accH;
  }
  __syncthreads();

  // ---- phase 3: skip + LayerNorm over 512 features ----
  const size_t xo = ((size_t)b * NN + i) * HF;
  float u0 = hacc[t] + x[xo + t];
  float u1 = hacc[t + 256] + x[xo + t + 256];
  float s = u0 + u1, ss = u0 * u0 + u1 * u1;
#pragma unroll
  for (int sft = 32; sft > 0; sft >>= 1) {
    s += __shfl_xor(s, sft);
    ss += __shfl_xor(ss, sft);
  }
  if (lane == 0) {
    rs[wave] = s;
    rss[wave] = ss;
  }
  __syncthreads();
  const float S = rs[0] + rs[1] + rs[2] + rs[3];
  const float SS = rss[0] + rss[1] + rss[2] + rss[3];
  const float mu = S * (1.0f / 512.0f);
  const float var = SS * (1.0f / 512.0f) - mu * mu;
  const float rstd = rsqrtf(var + 1e-5f);
  out[xo + t] = (u0 - mu) * rstd * gamma[t] + beta[t];
  out[xo + t + 256] = (u1 - mu) * rstd * gamma[t + 256] + beta[t + 256];
}

extern "C" void kernel_launch(void* const* d_in, const int* in_sizes, int n_in,
                              void* d_out, int out_size, void* d_ws,
                              size_t ws_size, hipStream_t stream) {
  const float* x = (const float*)d_in[0];
  const void* adj = d_in[1];
  const float* W = (const float*)d_in[2];
  const float* a = (const float*)d_in[3];
  const float* gamma = (const float*)d_in[4];
  const float* beta = (const float*)d_in[5];
  float* out = (float*)d_out;

  char* ws = (char*)d_ws;
  int* flag = (int*)ws;
  unsigned short* Wh = (unsigned short*)(ws + 256);                 // 8 MB
  unsigned short* Wt = (unsigned short*)(ws + 256 + 8388608);       // 0.5 MB
  float* e_src = (float*)(ws + 256 + 8388608 + 524288);             // 256 KB
  float* e_dst = e_src + (size_t)BB * NN * HH;                      // 256 KB

  k_detect<<<1, 64, 0, stream>>>(adj, flag);
  k_prep<<<dim3(8, 8), 256, 0, stream>>>(W, Wt);
  k_gemm<<<dim3(128, 8), 256, 0, stream>>>(x, Wt, Wh);
  k_edge<<<2048, 256, 0, stream>>>(Wh, a, e_src, e_dst);
  k_attn<<<BB * NN, 256, 0, stream>>>(x, adj, flag, Wh, e_src, e_dst, gamma,
                                      beta, out);
}

// Round 3
// 73.711 us; speedup vs baseline: 2.2692x; 1.0855x over previous
//
#include <hip/hip_runtime.h>
#include <hip/hip_bf16.h>

#define BB 8
#define NN 1024
#define FIN 512
#define HH 8
#define FOUT 64
#define HF 512
#define SLOPE 0.2f
#define ECAP 96

typedef __attribute__((ext_vector_type(8))) short bf16x8;
typedef __attribute__((ext_vector_type(4))) float f32x4;
typedef unsigned long long ull;

static __device__ __forceinline__ float lrelu(float v) { return v > 0.0f ? v : SLOPE * v; }

static __device__ __forceinline__ unsigned short f2bf(float f) {
  __hip_bfloat16 h = __float2bfloat16(f);
  return *reinterpret_cast<unsigned short*>(&h);
}
static __device__ __forceinline__ float bflo(unsigned v) {
  unsigned u = v << 16;
  return *reinterpret_cast<float*>(&u);
}
static __device__ __forceinline__ float bfhi(unsigned v) {
  unsigned u = v & 0xffff0000u;
  return *reinterpret_cast<float*>(&u);
}

// ---------------------------------------------------------------------------
// K1: transpose + cast W (FIN x HF, f32) -> Wt (HF x FIN, bf16).
// Block (0,0) thread 0 also detects adjacency dtype via the self-loop diag.
// mode 1 = int32, mode 2 = float32, mode 0 = 1-byte bool
// ---------------------------------------------------------------------------
__global__ __launch_bounds__(256) void k_prep(const float* __restrict__ W,
                                              unsigned short* __restrict__ Wt,
                                              const void* __restrict__ adj,
                                              int* __restrict__ flag) {
  if (blockIdx.x == 0 && blockIdx.y == 0 && threadIdx.x == 0) {
    const int* ai = (const int*)adj;
    const float* af = (const float*)adj;
    bool oki = true, okf = true;
    for (int i = 0; i < 64; ++i) {
      int d = i * (NN + 1);
      oki = oki && (ai[d] == 1);
      okf = okf && (af[d] == 1.0f);
    }
    *flag = oki ? 1 : (okf ? 2 : 0);
  }
  __shared__ float tile[64][65];
  const int t = threadIdx.x;
  const int r0 = blockIdx.y * 64, c0 = blockIdx.x * 64;
#pragma unroll
  for (int p = 0; p < 16; ++p) {
    int r = (t >> 6) + p * 4;
    tile[t & 63][r] = W[(size_t)(r0 + r) * HF + c0 + (t & 63)];
  }
  __syncthreads();
#pragma unroll
  for (int p = 0; p < 16; ++p) {
    int cc = (t >> 6) + p * 4;
    int rr = t & 63;
    Wt[(size_t)(c0 + cc) * FIN + r0 + rr] = f2bf(tile[cc][rr]);
  }
}

// ---------------------------------------------------------------------------
// K2: Wh = x @ W via bf16 MFMA, 64x64x64 tile, 256 thr (2x2 waves).
// Fused epilogue: e_src/e_dst from fp32 accumulators (shfl + LDS combine).
// ---------------------------------------------------------------------------
__global__ __launch_bounds__(256) void k_gemm(const float* __restrict__ x,
                                              const unsigned short* __restrict__ Wt,
                                              const float* __restrict__ a,
                                              unsigned short* __restrict__ Wh,
                                              float* __restrict__ e_src,
                                              float* __restrict__ e_dst) {
  __shared__ short As[64 * 64];
  __shared__ short Bs[64 * 64];
  __shared__ float eps[2][64], epd[2][64];

  const int t = threadIdx.x;
  const int wave = t >> 6, lane = t & 63;
  const int wr = wave >> 1, wc = wave & 1;
  const int row0 = blockIdx.x * 64, col0 = blockIdx.y * 64;
  const int bn = blockIdx.y;  // head

  f32x4 acc[2][2] = {};

  const int sr = t >> 3;
  const int skc = t & 7;

  for (int k0 = 0; k0 < FIN; k0 += 64) {
    __syncthreads();
#pragma unroll
    for (int ss = 0; ss < 2; ++ss) {
      const int row = sr + ss * 32;
      const int ksrc = k0 + ((skc ^ (row & 7)) << 3);
      const float4* g = (const float4*)(x + (size_t)(row0 + row) * FIN + ksrc);
      float4 v0 = g[0], v1 = g[1];
      bf16x8 pk;
      unsigned short* u = (unsigned short*)&pk;
      u[0] = f2bf(v0.x); u[1] = f2bf(v0.y); u[2] = f2bf(v0.z); u[3] = f2bf(v0.w);
      u[4] = f2bf(v1.x); u[5] = f2bf(v1.y); u[6] = f2bf(v1.z); u[7] = f2bf(v1.w);
      *(bf16x8*)(&As[row * 64 + skc * 8]) = pk;

      uint4 wv = *(const uint4*)(Wt + (size_t)(col0 + row) * FIN + ksrc);
      *(uint4*)(&Bs[row * 64 + skc * 8]) = wv;
    }
    __syncthreads();
#pragma unroll
    for (int s = 0; s < 2; ++s) {
      const int kc = s * 4 + (lane >> 4);
      bf16x8 af[2], bfr[2];
#pragma unroll
      for (int m = 0; m < 2; ++m) {
        const int row = wr * 32 + m * 16 + (lane & 15);
        af[m] = *(const bf16x8*)(&As[row * 64 + (kc ^ (row & 7)) * 8]);
      }
#pragma unroll
      for (int n = 0; n < 2; ++n) {
        const int col = wc * 32 + n * 16 + (lane & 15);
        bfr[n] = *(const bf16x8*)(&Bs[col * 64 + (kc ^ (col & 7)) * 8]);
      }
#pragma unroll
      for (int m = 0; m < 2; ++m)
#pragma unroll
        for (int n = 0; n < 2; ++n)
          acc[m][n] = __builtin_amdgcn_mfma_f32_16x16x32_bf16(af[m], bfr[n], acc[m][n], 0, 0, 0);
    }
  }

  // Wh store (C/D: col=lane&15, row=(lane>>4)*4+r)
#pragma unroll
  for (int m = 0; m < 2; ++m)
#pragma unroll
    for (int n = 0; n < 2; ++n)
#pragma unroll
      for (int r = 0; r < 4; ++r) {
        const int row = row0 + wr * 32 + m * 16 + (lane >> 4) * 4 + r;
        const int col = col0 + wc * 32 + n * 16 + (lane & 15);
        Wh[(size_t)row * HF + col] = f2bf(acc[m][n][r]);
      }

  // fused e_src/e_dst epilogue
  float av_s[2], av_d[2];
#pragma unroll
  for (int n = 0; n < 2; ++n) {
    const int cl = wc * 32 + n * 16 + (lane & 15);
    av_s[n] = a[bn * 2 * FOUT + cl];
    av_d[n] = a[bn * 2 * FOUT + FOUT + cl];
  }
#pragma unroll
  for (int m = 0; m < 2; ++m)
#pragma unroll
    for (int r = 0; r < 4; ++r) {
      float ps = acc[m][0][r] * av_s[0] + acc[m][1][r] * av_s[1];
      float pd = acc[m][0][r] * av_d[0] + acc[m][1][r] * av_d[1];
#pragma unroll
      for (int s = 1; s < 16; s <<= 1) {
        ps += __shfl_xor(ps, s);
        pd += __shfl_xor(pd, s);
      }
      if ((lane & 15) == 0) {
        const int rl = wr * 32 + m * 16 + (lane >> 4) * 4 + r;
        eps[wc][rl] = ps;
        epd[wc][rl] = pd;
      }
    }
  __syncthreads();
  if (t < 64) {
    e_src[(size_t)(row0 + t) * HH + bn] = eps[0][t] + eps[1][t];
    e_dst[(size_t)(row0 + t) * HH + bn] = epd[0][t] + epd[1][t];
  }
}

// ---------------------------------------------------------------------------
// K3: fused sparse attention + skip + LayerNorm.
// One WAVE per (b,i) row, 4 rows per block, zero __syncthreads.
// ---------------------------------------------------------------------------
__global__ __launch_bounds__(256) void k_attn(
    const float* __restrict__ x, const void* __restrict__ adj,
    const int* __restrict__ flag, const unsigned short* __restrict__ Wh,
    const float* __restrict__ e_src, const float* __restrict__ e_dst,
    const float* __restrict__ gamma, const float* __restrict__ beta,
    float* __restrict__ out) {
  __shared__ unsigned short nbrs[4][NN];
  __shared__ float edbuf[4][ECAP * 8];
  __shared__ float esb[4][8], erm[4][8], einv[4][8];

  const int wave = threadIdx.x >> 6, lane = threadIdx.x & 63;
  const int gr = blockIdx.x * 4 + wave;     // global row = b*NN + i
  const int bN = (gr >> 10) << 10;          // b*NN
  const size_t arow = (size_t)gr << 10;
  const int mode = *flag;

  unsigned short* nb = nbrs[wave];
  float* ed = edbuf[wave];

  // ---- phase 1: in-wave neighbor compaction (4 rounds x 4 ballots) ----
  int off = 0;
#pragma unroll
  for (int rr = 0; rr < 4; ++rr) {
    const int j0 = rr * 256 + lane * 4;
    bool v0, v1, v2, v3;
    if (mode == 1) {
      int4 q = *((const int4*)((const int*)adj + arow + j0));
      v0 = q.x != 0; v1 = q.y != 0; v2 = q.z != 0; v3 = q.w != 0;
    } else if (mode == 2) {
      float4 q = *((const float4*)((const float*)adj + arow + j0));
      v0 = q.x != 0.f; v1 = q.y != 0.f; v2 = q.z != 0.f; v3 = q.w != 0.f;
    } else {
      unsigned q = *((const unsigned*)((const unsigned char*)adj + arow + j0));
      v0 = (q & 0xffu) != 0; v1 = (q & 0xff00u) != 0;
      v2 = (q & 0xff0000u) != 0; v3 = (q >> 24) != 0;
    }
    ull m0 = __ballot(v0), m1 = __ballot(v1);
    ull m2 = __ballot(v2), m3 = __ballot(v3);
    const ull below = (1ull << lane) - 1ull;
    int base = off + __popcll(m0 & below) + __popcll(m1 & below) +
               __popcll(m2 & below) + __popcll(m3 & below);
    int c = 0;
    if (v0) nb[base + c++] = (unsigned short)(j0 + 0);
    if (v1) nb[base + c++] = (unsigned short)(j0 + 1);
    if (v2) nb[base + c++] = (unsigned short)(j0 + 2);
    if (v3) nb[base + c++] = (unsigned short)(j0 + 3);
    off += __popcll(m0) + __popcll(m1) + __popcll(m2) + __popcll(m3);
  }
  const int total = off;
  const int ncap = total < ECAP ? total : ECAP;

  // ---- phase 2: gather e_dst (lane = (kq, h)), softmax all 8 heads ----
  const int h = lane & 7, kq = lane >> 3;
  for (int k = kq; k < ncap; k += 8)
    ed[k * 8 + h] = e_dst[(size_t)(bN + nb[k]) * HH + h];

  const float es = e_src[(size_t)gr * HH + h];
  float mx = -1e30f;
  for (int k = kq; k < total; k += 8) {
    float v = (k < ECAP) ? ed[k * 8 + h] : e_dst[(size_t)(bN + nb[k]) * HH + h];
    mx = fmaxf(mx, v);
  }
  mx = fmaxf(mx, __shfl_xor(mx, 8));
  mx = fmaxf(mx, __shfl_xor(mx, 16));
  mx = fmaxf(mx, __shfl_xor(mx, 32));
  const float rm = lrelu(es + mx);

  float z = 0.0f;
  for (int k = kq; k < total; k += 8) {
    float v = (k < ECAP) ? ed[k * 8 + h] : e_dst[(size_t)(bN + nb[k]) * HH + h];
    float w = __expf(lrelu(es + v) - rm);
    if (k < ECAP) ed[k * 8 + h] = w;   // unscaled weight
    z += w;
  }
  z += __shfl_xor(z, 8);
  z += __shfl_xor(z, 16);
  z += __shfl_xor(z, 32);
  if (kq == 0) {
    esb[wave][h] = es;
    erm[wave][h] = rm;
    einv[wave][h] = 1.0f / z;
  }

  // ---- phase 3: weighted feature accumulation; lane owns 8 features ----
  const int h2 = lane >> 3;
  const float es2 = esb[wave][h2], rm2 = erm[wave][h2];
  const int feat = lane * 8;
  float a0 = 0, a1 = 0, a2 = 0, a3 = 0, a4 = 0, a5 = 0, a6 = 0, a7 = 0;
#pragma unroll 2
  for (int k = 0; k < total; ++k) {
    const int j = nb[k];
    float w;
    if (k < ECAP)
      w = ed[k * 8 + h2];
    else
      w = __expf(lrelu(es2 + e_dst[(size_t)(bN + j) * HH + h2]) - rm2);
    uint4 q = *(const uint4*)(Wh + (size_t)(bN + j) * HF + feat);
    a0 += w * bflo(q.x); a1 += w * bfhi(q.x);
    a2 += w * bflo(q.y); a3 += w * bfhi(q.y);
    a4 += w * bflo(q.z); a5 += w * bfhi(q.z);
    a6 += w * bflo(q.w); a7 += w * bfhi(q.w);
  }
  const float inv = einv[wave][h2];

  // ---- phase 4: skip + LayerNorm (512 feats across the wave) ----
  const size_t xo = (size_t)gr * HF + feat;
  float4 xv0 = *(const float4*)(x + xo);
  float4 xv1 = *(const float4*)(x + xo + 4);
  float v0 = a0 * inv + xv0.x, v1 = a1 * inv + xv0.y;
  float v2 = a2 * inv + xv0.z, v3 = a3 * inv + xv0.w;
  float v4 = a4 * inv + xv1.x, v5 = a5 * inv + xv1.y;
  float v6 = a6 * inv + xv1.z, v7 = a7 * inv + xv1.w;

  float s = v0 + v1 + v2 + v3 + v4 + v5 + v6 + v7;
  float ss = v0 * v0 + v1 * v1 + v2 * v2 + v3 * v3 +
             v4 * v4 + v5 * v5 + v6 * v6 + v7 * v7;
#pragma unroll
  for (int sft = 1; sft < 64; sft <<= 1) {
    s += __shfl_xor(s, sft);
    ss += __shfl_xor(ss, sft);
  }
  const float mu = s * (1.0f / 512.0f);
  const float var = ss * (1.0f / 512.0f) - mu * mu;
  const float rstd = rsqrtf(var + 1e-5f);

  float4 g0 = *(const float4*)(gamma + feat);
  float4 g1 = *(const float4*)(gamma + feat + 4);
  float4 b0 = *(const float4*)(beta + feat);
  float4 b1 = *(const float4*)(beta + feat + 4);
  float4 o0, o1;
  o0.x = (v0 - mu) * rstd * g0.x + b0.x;
  o0.y = (v1 - mu) * rstd * g0.y + b0.y;
  o0.z = (v2 - mu) * rstd * g0.z + b0.z;
  o0.w = (v3 - mu) * rstd * g0.w + b0.w;
  o1.x = (v4 - mu) * rstd * g1.x + b1.x;
  o1.y = (v5 - mu) * rstd * g1.y + b1.y;
  o1.z = (v6 - mu) * rstd * g1.z + b1.z;
  o1.w = (v7 - mu) * rstd * g1.w + b1.w;
  *(float4*)(out + xo) = o0;
  *(float4*)(out + xo + 4) = o1;
}

extern "C" void kernel_launch(void* const* d_in, const int* in_sizes, int n_in,
                              void* d_out, int out_size, void* d_ws,
                              size_t ws_size, hipStream_t stream) {
  const float* x = (const float*)d_in[0];
  const void* adj = d_in[1];
  const float* W = (const float*)d_in[2];
  const float* a = (const float*)d_in[3];
  const float* gamma = (const float*)d_in[4];
  const float* beta = (const float*)d_in[5];
  float* out = (float*)d_out;

  char* ws = (char*)d_ws;
  int* flag = (int*)ws;
  unsigned short* Wh = (unsigned short*)(ws + 256);                 // 8 MB
  unsigned short* Wt = (unsigned short*)(ws + 256 + 8388608);       // 0.5 MB
  float* e_src = (float*)(ws + 256 + 8388608 + 524288);             // 256 KB
  float* e_dst = e_src + (size_t)BB * NN * HH;                      // 256 KB

  k_prep<<<dim3(8, 8), 256, 0, stream>>>(W, Wt, adj, flag);
  k_gemm<<<dim3(128, 8), 256, 0, stream>>>(x, Wt, a, Wh, e_src, e_dst);
  k_attn<<<2048, 256, 0, stream>>>(x, adj, flag, Wh, e_src, e_dst, gamma,
                                   beta, out);
}